// Round 9
// baseline (2076.831 us; speedup 1.0000x reference)
//
#include <hip/hip_runtime.h>

// Problem constants (match reference)
#define SEQ 2048
#define BAT 256
#define KD  64
#define HD  128
#define NB  16      // batch elements per workgroup -> 16 WGs
#define CH  128     // dt/seq_types LDS chunk length (steps)
#define HSTR 136    // h-state row stride in f16 units (272 B, 16B-aligned)

typedef __fp16 f16x8  __attribute__((ext_vector_type(8)));   // MFMA A/B frag
typedef float  f32x4  __attribute__((ext_vector_type(4)));   // MFMA C/D frag
typedef __fp16 fp16x2 __attribute__((ext_vector_type(2)));   // cvt_pkrtz ret

// Pack two f32 -> f16x2 bits (v_cvt_pkrtz_f16_f32).
__device__ __forceinline__ int PK(float a, float b) {
    fp16x2 p = __builtin_amdgcn_cvt_pkrtz(a, b);
    return __builtin_bit_cast(int, p);
}

// Pin a scalar into a register (loads can't sink past the volatile asm).
#define PIN(x) asm volatile("" : "+v"(x))

// LDS-visibility-only barrier: does NOT drain vmcnt (output stores stay in
// flight; they need no ordering with the barrier).
#define STEP_BARRIER() do {                                   \
    asm volatile("s_waitcnt lgkmcnt(0)" ::: "memory");        \
    __builtin_amdgcn_s_barrier();                             \
    asm volatile("" ::: "memory");                            \
} while (0)

// ---------------------------------------------------------------------------
// Kernel 1: precompute type-dependent tables into d_ws (f32).
//   tabH[ty][r] = sum_k embed_W[ty][k]*W_ih[r][k] + b_ih[r] + b_hh[r]
//   tabD[ty][r] = sum_k embed_W[ty][k]*dec_W[r][k] + dec_b[r]
// ---------------------------------------------------------------------------
__global__ __launch_bounds__(128) void precompute_tables(
    const float* __restrict__ embed_W, const float* __restrict__ W_ih,
    const float* __restrict__ b_ih,    const float* __restrict__ b_hh,
    const float* __restrict__ dec_W,   const float* __restrict__ dec_b,
    float* __restrict__ tabH, float* __restrict__ tabD)
{
    __shared__ float x[KD];
    const int ty = blockIdx.x;   // 0..64 (row 64 = padding, embed row is zero)
    const int r  = threadIdx.x;  // 0..127
    if (r < KD) x[r] = embed_W[ty * KD + r];
    __syncthreads();
    float ah = 0.f, ad = 0.f;
#pragma unroll
    for (int k = 0; k < KD; ++k) {
        const float xv = x[k];
        ah += xv * W_ih[r * KD + k];
        ad += xv * dec_W[r * (KD + HD) + k];
    }
    tabH[ty * HD + r] = ah + b_ih[r] + b_hh[r];
    tabD[ty * HD + r] = ad + dec_b[r];
}

// ---------------------------------------------------------------------------
// Kernel 2: MFMA recurrence. 16 WGs x 512 threads; WG owns 16 batch elements.
// Per step: D[16 batch][256 outs] = h[16][128] @ W^T via mfma_f32_16x16x32_f16.
// Wave w owns hidden N-tile w (out cols 16w..16w+15) AND decay N-tile 8+w
// (same cols) -> C fragments pair (H,D) per (batch,col) in-lane.
// Fragment maps (gfx950): A: row=lane&15 (batch), k=32ks+8*(lane>>4)+j.
//                         B: col=lane&15 (out),   k same -> W row slice.
//                         C/D: col=lane&15, row=(lane>>4)*4+reg (batch).
// Bias tables folded into C init. h state f16 in LDS, double-buffered.
// dt / seq_types staged in 128-step LDS chunks (double-buffered).
// ---------------------------------------------------------------------------
__global__ __launch_bounds__(512, 1) void hawkes_rnn(
    const float* __restrict__ dt_g,  const float* __restrict__ h0,
    const float* __restrict__ W_hh,  const float* __restrict__ dec_W,
    const int*   __restrict__ seq_types,
    const float* __restrict__ tabH,  const float* __restrict__ tabD,
    float* __restrict__ out)
{
    __shared__ float tabF[2][KD + 1][HD + 1];        // 67,080 B (f32, +1 pad)
    __shared__ float dtc[2][CH][NB];                 // 16,384 B
    __shared__ int   tyc[2][CH][NB];                 // 16,384 B
    __shared__ __align__(16) __fp16 hst[2][NB][HSTR]; // 8,704 B

    const int b0   = blockIdx.x * NB;
    const int tid  = threadIdx.x;
    const int lane = tid & 63;
    const int w    = tid >> 6;        // wave 0..7
    const int lr   = lane & 15;       // A row / B col / C col
    const int lg   = lane >> 4;       // k-group / C row group
    const int colh = 16 * w + lr;     // output column (0..127 in each half)

    // ---- stage bias tables into LDS ----
    for (int i = tid; i < (KD + 1) * HD; i += 512) {
        const int r = i >> 7, c = i & (HD - 1);
        tabF[0][r][c] = tabH[i];
        tabF[1][r][c] = tabD[i];
    }
    // ---- stage h0 (f32 -> f16) ----
    for (int i = tid; i < NB * HD; i += 512) {
        const int r = i >> 7, c = i & (HD - 1);
        hst[0][r][c] = (__fp16)h0[(b0 + r) * HD + c];
    }
    // ---- stage chunk 0 of dt / seq_types ----
    for (int i = tid; i < CH * NB; i += 512) {
        const int r = i >> 4, c = i & (NB - 1);
        dtc[0][r][c] = dt_g[(size_t)r * BAT + b0 + c];
        tyc[0][r][c] = seq_types[(size_t)r * BAT + b0 + c];
    }

    // ---- B fragments (weights) -> f16 pairs in pinned registers ----
    // hidden: W_hh[colh][k], decay: dec_W[colh][KD + k]; k = 32ks + 8lg + j.
    const float* whrow = W_hh  + (size_t)colh * HD + 8 * lg;
    const float* wdrow = dec_W + (size_t)colh * (KD + HD) + KD + 8 * lg;
    int4 bh[4], bd[4];
#pragma unroll
    for (int ks = 0; ks < 4; ++ks) {
        float4 x = *reinterpret_cast<const float4*>(whrow + 32 * ks);
        float4 y = *reinterpret_cast<const float4*>(whrow + 32 * ks + 4);
        bh[ks] = make_int4(PK(x.x, x.y), PK(x.z, x.w), PK(y.x, y.y), PK(y.z, y.w));
        x = *reinterpret_cast<const float4*>(wdrow + 32 * ks);
        y = *reinterpret_cast<const float4*>(wdrow + 32 * ks + 4);
        bd[ks] = make_int4(PK(x.x, x.y), PK(x.z, x.w), PK(y.x, y.y), PK(y.z, y.w));
    }
#pragma unroll
    for (int ks = 0; ks < 4; ++ks) {
        PIN(bh[ks].x); PIN(bh[ks].y); PIN(bh[ks].z); PIN(bh[ks].w);
        PIN(bd[ks].x); PIN(bd[ks].y); PIN(bd[ks].z); PIN(bd[ks].w);
    }

    // ---- strength-reduced output pointers (advance BAT*HD per step) ----
    float* hidp = out + (size_t)(b0 + 4 * lg) * HD + colh;
    float* decp = hidp + (size_t)SEQ * BAT * HD;
    float* htip = decp + (size_t)SEQ * BAT * HD;

    __syncthreads();   // all staging visible

#define RNN_STEP(P) { \
    const float4 dt4 = *reinterpret_cast<const float4*>(dtb + (size_t)i * NB); \
    const int4   ty4 = *reinterpret_cast<const int4*>  (tyb + (size_t)i * NB); \
    f32x4 accH, accD;  /* C init = bias tables (MFMA adds on top) */ \
    accH[0] = tabF[0][ty4.x][colh]; accD[0] = tabF[1][ty4.x][colh]; \
    accH[1] = tabF[0][ty4.y][colh]; accD[1] = tabF[1][ty4.y][colh]; \
    accH[2] = tabF[0][ty4.z][colh]; accD[2] = tabF[1][ty4.z][colh]; \
    accH[3] = tabF[0][ty4.w][colh]; accD[3] = tabF[1][ty4.w][colh]; \
    _Pragma("unroll") \
    for (int ks = 0; ks < 4; ++ks) { \
        const f16x8 a = __builtin_bit_cast(f16x8, \
            *reinterpret_cast<const int4*>(&hst[P][lr][32 * ks + 8 * lg])); \
        accH = __builtin_amdgcn_mfma_f32_16x16x32_f16( \
                   a, __builtin_bit_cast(f16x8, bh[ks]), accH, 0, 0, 0); \
        accD = __builtin_amdgcn_mfma_f32_16x16x32_f16( \
                   a, __builtin_bit_cast(f16x8, bd[ks]), accD, 0, 0, 0); \
    } \
    _Pragma("unroll") \
    for (int q = 0; q < 4; ++q) { \
        const float H = accH[q], D = accD[q]; \
        const float dtq = (q == 0) ? dt4.x : (q == 1) ? dt4.y \
                        : (q == 2) ? dt4.z : dt4.w; \
        const float e2 = __expf(2.f * H); \
        const float vh = 1.f - __fdividef(2.f, e2 + 1.f);        /* tanh */ \
        const float z  = 10.f * D; \
        const float em = __expf(-fabsf(z)); \
        const float sp = 0.1f * (fmaxf(z, 0.f) + __logf(1.f + em)); \
        const float vd = __expf(-sp * dtq); \
        const float hnew = vh * vd; \
        hidp[q * HD] = vh; \
        decp[q * HD] = sp; \
        htip[q * HD] = hnew; \
        hst[(P) ^ 1][4 * lg + q][colh] = (__fp16)hnew; \
    } \
    hidp += BAT * HD; decp += BAT * HD; htip += BAT * HD; \
    STEP_BARRIER(); \
}

    for (int ch = 0; ch < SEQ / CH; ++ch) {
        const int cb = ch & 1;
        // stage NEXT chunk (uniform condition; writes land well before use)
        if (ch + 1 < SEQ / CH) {
            const int t1 = (ch + 1) * CH;
#pragma unroll
            for (int k = 0; k < (CH * NB) / 512; ++k) {
                const int i = tid + k * 512;
                const int r = i >> 4, c = i & (NB - 1);
                dtc[cb ^ 1][r][c] = dt_g[(size_t)(t1 + r) * BAT + b0 + c];
                tyc[cb ^ 1][r][c] = seq_types[(size_t)(t1 + r) * BAT + b0 + c];
            }
        }
        const float* dtb = &dtc[cb][0][4 * lg];
        const int*   tyb = &tyc[cb][0][4 * lg];

        for (int i0 = 0; i0 < CH; i0 += 2) {
            { const int i = i0;     RNN_STEP(0) }
            { const int i = i0 + 1; RNN_STEP(1) }
        }
    }
#undef RNN_STEP
}

extern "C" void kernel_launch(void* const* d_in, const int* in_sizes, int n_in,
                              void* d_out, int out_size, void* d_ws, size_t ws_size,
                              hipStream_t stream) {
    const float* dt        = (const float*)d_in[0];
    const float* h0        = (const float*)d_in[1];
    const float* embed_W   = (const float*)d_in[2];
    const float* W_ih      = (const float*)d_in[3];
    const float* b_ih      = (const float*)d_in[4];
    const float* W_hh      = (const float*)d_in[5];
    const float* b_hh      = (const float*)d_in[6];
    const float* dec_W     = (const float*)d_in[7];
    const float* dec_b     = (const float*)d_in[8];
    const int*   seq_types = (const int*)  d_in[9];
    float* out  = (float*)d_out;

    float* tabHw = (float*)d_ws;                 // [65][128]
    float* tabDw = tabHw + (KD + 1) * HD;        // [65][128]

    precompute_tables<<<KD + 1, 128, 0, stream>>>(embed_W, W_ih, b_ih, b_hh,
                                                  dec_W, dec_b, tabHw, tabDw);
    hawkes_rnn<<<BAT / NB, 512, 0, stream>>>(dt, h0, W_hh, dec_W, seq_types,
                                             tabHw, tabDw, out);
}

// Round 10
// 1136.855 us; speedup vs baseline: 1.8268x; 1.8268x over previous
//
#include <hip/hip_runtime.h>

// Problem constants (match reference)
#define SEQ 2048
#define BAT 256
#define KD  64
#define HD  128
#define WSTR 36   // per-lane weight-block stride in dwords (144 B: 8x16B + 16B pad
                  //  -> lane base bank = (36*l)%32 = 4l%32, conflict-free b128 reads)

typedef _Float16 half2v  __attribute__((ext_vector_type(2)));  // fdot2 operand type
typedef __fp16   fp16x2  __attribute__((ext_vector_type(2)));  // cvt_pkrtz return type

// DPP helpers. CTRL: 0xB1 = quad_perm(1,0,3,2) = lane^1; 0x4E = quad_perm(2,3,0,1)
// = lane^2; 0x128 = row_ror:8 = lane^8 within 16-lane row; 0x124/0x12C =
// row_ror:4 / row_ror:12 (together + select = lane^4 exchange).
template<int CTRL>
__device__ __forceinline__ float dpp_add(float keep, float send) {
    const int r = __builtin_amdgcn_update_dpp(0, __float_as_int(send),
                                              CTRL, 0xF, 0xF, true);
    return keep + __int_as_float(r);
}
template<int CTRL>
__device__ __forceinline__ float dpp_mov(float send) {
    const int r = __builtin_amdgcn_update_dpp(0, __float_as_int(send),
                                              CTRL, 0xF, 0xF, true);
    return __int_as_float(r);
}

// Pack two f32 -> f16x2 bits (v_cvt_pkrtz_f16_f32).
__device__ __forceinline__ int PK(float a, float b) {
    fp16x2 p = __builtin_amdgcn_cvt_pkrtz(a, b);
    return __builtin_bit_cast(int, p);
}

// f32 += dot2(f16x2, f16x2) — v_dot2_f32_f16, f32 accumulate.
__device__ __forceinline__ float fdot2(int w, int h, float c) {
#if __has_builtin(__builtin_amdgcn_fdot2)
    return __builtin_amdgcn_fdot2(__builtin_bit_cast(half2v, w),
                                  __builtin_bit_cast(half2v, h), c, false);
#else
    half2v wv = __builtin_bit_cast(half2v, w), hv = __builtin_bit_cast(half2v, h);
    return fmaf((float)wv[1], (float)hv[1], fmaf((float)wv[0], (float)hv[0], c));
#endif
}

// LDS-visibility-only barrier: does NOT drain vmcnt (output stores stay in
// flight). The "memory" clobber also forces the weight ds_reads to stay
// INSIDE the loop (no LICM back into long-lived registers -> no AGPR games).
#define STEP_BARRIER() do {                                   \
    asm volatile("s_waitcnt lgkmcnt(0)" ::: "memory");        \
    __builtin_amdgcn_s_barrier();                             \
    asm volatile("" ::: "memory");                            \
} while (0)

// ---------------------------------------------------------------------------
// Kernel 1: precompute type-dependent tables into d_ws (f32).
//   tabH[ty][r] = sum_k embed_W[ty][k]*W_ih[r][k] + b_ih[r] + b_hh[r]
//   tabD[ty][r] = sum_k embed_W[ty][k]*dec_W[r][k] + dec_b[r]
// ---------------------------------------------------------------------------
__global__ __launch_bounds__(128) void precompute_tables(
    const float* __restrict__ embed_W, const float* __restrict__ W_ih,
    const float* __restrict__ b_ih,    const float* __restrict__ b_hh,
    const float* __restrict__ dec_W,   const float* __restrict__ dec_b,
    float* __restrict__ tabH, float* __restrict__ tabD)
{
    __shared__ float x[KD];
    const int ty = blockIdx.x;   // 0..64 (row 64 = padding, embed row is zero)
    const int r  = threadIdx.x;  // 0..127
    if (r < KD) x[r] = embed_W[ty * KD + r];
    __syncthreads();
    float ah = 0.f, ad = 0.f;
#pragma unroll
    for (int k = 0; k < KD; ++k) {
        const float xv = x[k];
        ah += xv * W_ih[r * KD + k];
        ad += xv * dec_W[r * (KD + HD) + k];
    }
    tabH[ty * HD + r] = ah + b_ih[r] + b_hh[r];
    tabD[ty * HD + r] = ad + dec_b[r];
}

// ---------------------------------------------------------------------------
// Kernel 2: persistent per-batch-element recurrence. One WG per batch elem,
// 512 threads = 8 waves. Lane bits (lane = tid&63):
//   b0,b1: row-low bits AND chunk bits 0,1 (value-halving butterfly)
//   b2: type (0=hidden/W_hh, 1=decay/dec_W)
//   b3: chunk bit 2 / duplicate tag
//   bits4-5 + wave: row quad G = wave*4 + ((lane>>4)&3)
// chunk = b0|b1<<1|b3<<2 (8 chunks x 16 h-cols); row = 4G + 2*b0 + b1.
// WEIGHTS LIVE IN LDS (f16, 144B-stride per-lane blocks): staged once, re-read
// with 8 conflict-free ds_read_b128 per step. This removes the pinned-register
// path whose AGPR allocation caused ~2-3x VALU inst inflation (rounds 4-8).
// Reduction all-DPP: xor1/xor2 value-halving, xor8 plain add. Type exchange
// lane^4 via row_ror:4/12 + select. Each lane does EXACTLY ONE output task.
// h double-buffered in LDS f16; ONE lgkm-only barrier per step; 2x unrolled.
// ---------------------------------------------------------------------------
__global__ __launch_bounds__(512, 2) void hawkes_rnn(
    const float* __restrict__ dt_g,  const float* __restrict__ h0,
    const float* __restrict__ W_hh,  const float* __restrict__ dec_W,
    const int*   __restrict__ seq_types,
    const float* __restrict__ tabH,  const float* __restrict__ tabD,
    float* __restrict__ out)
{
    __shared__ int   wlds[512 * WSTR];               // 73,728 B weight home
    __shared__ float dts[SEQ];                       //  8,192 B
    __shared__ int   tys[SEQ + 2];                   //  8,200 B
    __shared__ __align__(16) _Float16 h16[2][HD];    //    512 B

    const int b    = blockIdx.x;
    const int tid  = threadIdx.x;
    const int lane = tid & 63;
    const int b0 = lane & 1, b1 = (lane >> 1) & 1;
    const int b2 = (lane >> 2) & 1, b3 = (lane >> 3) & 1;
    const int G    = (tid >> 6) * 4 + ((lane >> 4) & 3);  // row quad 0..31
    const int row  = 4 * G + 2 * b0 + b1;
    const int chunk = b0 | (b1 << 1) | (b3 << 2);         // h-col block /16
    const bool cls3 = (b2 & b3);                          // LDS-writer lane

    // Stage dt / seq_types columns for this batch element.
    for (int t = tid; t < SEQ; t += 512) {
        dts[t] = dt_g[(size_t)t * BAT + b];
        tys[t] = seq_types[(size_t)t * BAT + b];
    }
    if (tid < 2) tys[SEQ + tid] = 0;          // prefetch-pad
    if (tid < HD) h16[0][tid] = (_Float16)h0[b * HD + tid];

    // Stage this lane's weight block (4 rows x 16 cols, f32 -> f16x2) into its
    // LDS home. Slot 2r = cols 0-7 of row r, slot 2r+1 = cols 8-15.
    {
        const size_t rstr = b2 ? (size_t)(KD + HD) : (size_t)HD;
        const float* wb = (b2 ? (dec_W + KD) : W_hh) + (size_t)(4 * G) * rstr
                          + chunk * 16;
        int4* wdst = reinterpret_cast<int4*>(&wlds[tid * WSTR]);
#pragma unroll
        for (int r = 0; r < 4; ++r) {
            const float4 a = *reinterpret_cast<const float4*>(wb + r * rstr);
            const float4 bq = *reinterpret_cast<const float4*>(wb + r * rstr + 4);
            const float4 cq = *reinterpret_cast<const float4*>(wb + r * rstr + 8);
            const float4 dq = *reinterpret_cast<const float4*>(wb + r * rstr + 12);
            wdst[2 * r]     = make_int4(PK(a.x, a.y), PK(a.z, a.w),
                                        PK(bq.x, bq.y), PK(bq.z, bq.w));
            wdst[2 * r + 1] = make_int4(PK(cq.x, cq.y), PK(cq.z, cq.w),
                                        PK(dq.x, dq.y), PK(dq.z, dq.w));
        }
    }

    const float* tabp = (b2 ? tabD : tabH) + row;

    // Per-lane 32-bit element offset for the single global store this lane
    // owns (advanced by BAT*HD per step). Class 3 never stores.
    unsigned off = (unsigned)(b2 ? (b3 ? 0u : (unsigned)SEQ * BAT * HD)
                                 : (b3 ? 2u * SEQ * BAT * HD : 0u))
                   + (unsigned)(b * HD + row);

    __syncthreads();   // staging (dt/ty/h0/weights) visible

    // Table prefetch pipeline (2 steps ahead; tables are L2-resident).
    float tab_cur = tabp[tys[0] * HD];
    float tab_nxt = tabp[tys[1] * HD];

    const int4* wl = reinterpret_cast<const int4*>(&wlds[tid * WSTR]);

#define DOT8(A,WA,WB) \
    A = fdot2(WA.x, hv0.x, A); A = fdot2(WA.y, hv0.y, A); \
    A = fdot2(WA.z, hv0.z, A); A = fdot2(WA.w, hv0.w, A); \
    A = fdot2(WB.x, hv1.x, A); A = fdot2(WB.y, hv1.y, A); \
    A = fdot2(WB.z, hv1.z, A); A = fdot2(WB.w, hv1.w, A);

#define STEP(P, TT) { \
    const float tab_pf = tabp[tys[(TT) + 2] * HD];   /* use at TT+2 */ \
    const float dtv    = dts[TT]; \
    /* weights: 8 conflict-free ds_read_b128 from this lane's LDS home */ \
    const int4 W0 = wl[0], W1 = wl[1], W2 = wl[2], W3 = wl[3]; \
    const int4 W4 = wl[4], W5 = wl[5], W6 = wl[6], W7 = wl[7]; \
    /* h chunk: 2 broadcast ds_read_b128 */ \
    const int4 hv0 = *reinterpret_cast<const int4*>(&h16[P][chunk * 16]); \
    const int4 hv1 = *reinterpret_cast<const int4*>(&h16[P][chunk * 16 + 8]); \
    float a0 = 0.f, a1 = 0.f, a2 = 0.f, a3 = 0.f; \
    DOT8(a0, W0, W1) \
    DOT8(a1, W2, W3) \
    DOT8(a2, W4, W5) \
    DOT8(a3, W6, W7) \
    /* value-halving: xor1 resolves row-bit1, xor2 resolves row-bit0 */ \
    const float t0 = dpp_add<0xB1>(b0 ? a2 : a0, b0 ? a0 : a2); \
    const float t1 = dpp_add<0xB1>(b0 ? a3 : a1, b0 ? a1 : a3); \
    const float u  = dpp_add<0x4E>(b1 ? t1 : t0, b1 ? t0 : t1); \
    /* xor8 plain add completes the 8-chunk sum */ \
    const float sv = dpp_add<0x128>(u, u) + tab_cur; \
    /* activations (branchless; all lanes both paths) */ \
    const float e2 = __expf(2.f * sv); \
    const float vh = 1.f - __fdividef(2.f, e2 + 1.f);            /* tanh */ \
    const float z  = 10.f * sv; \
    const float em = __expf(-fabsf(z)); \
    const float sp = 0.1f * (fmaxf(z, 0.f) + __logf(1.f + em));  /* softplus10 */ \
    const float vd = __expf(-sp * dtv); \
    const float v  = b2 ? vd : vh; \
    /* type exchange lane^4: row_ror:4 / row_ror:12 + select */ \
    const float x4  = dpp_mov<0x124>(v); \
    const float x12 = dpp_mov<0x12C>(v); \
    const float cross = b2 ? x12 : x4; \
    const float hnew  = v * cross; \
    if (cls3) { \
        h16[(P) ^ 1][row] = (_Float16)hnew; \
    } else { \
        const float stv = b2 ? sp : (b3 ? hnew : v); \
        out[off] = stv; \
    } \
    off += BAT * HD; \
    tab_cur = tab_nxt; \
    tab_nxt = tab_pf; \
    STEP_BARRIER(); \
}

    for (int t = 0; t < SEQ; t += 2) {
        STEP(0, t)
        STEP(1, t + 1)
    }
#undef STEP
#undef DOT8
}

extern "C" void kernel_launch(void* const* d_in, const int* in_sizes, int n_in,
                              void* d_out, int out_size, void* d_ws, size_t ws_size,
                              hipStream_t stream) {
    const float* dt        = (const float*)d_in[0];
    const float* h0        = (const float*)d_in[1];
    const float* embed_W   = (const float*)d_in[2];
    const float* W_ih      = (const float*)d_in[3];
    const float* b_ih      = (const float*)d_in[4];
    const float* W_hh      = (const float*)d_in[5];
    const float* b_hh      = (const float*)d_in[6];
    const float* dec_W     = (const float*)d_in[7];
    const float* dec_b     = (const float*)d_in[8];
    const int*   seq_types = (const int*)  d_in[9];
    float* out  = (float*)d_out;

    float* tabHw = (float*)d_ws;                 // [65][128]
    float* tabDw = tabHw + (KD + 1) * HD;        // [65][128]

    precompute_tables<<<KD + 1, 128, 0, stream>>>(embed_W, W_ih, b_ih, b_hh,
                                                  dec_W, dec_b, tabHw, tabDw);
    hawkes_rnn<<<BAT, 512, 0, stream>>>(dt, h0, W_hh, dec_W, seq_types,
                                        tabHw, tabDw, out);
}

// Round 11
// 1060.567 us; speedup vs baseline: 1.9582x; 1.0719x over previous
//
#include <hip/hip_runtime.h>

// Problem constants (match reference)
#define SEQ 2048
#define BAT 256
#define KD  64
#define HD  128

// DPP helpers. CTRL: 0xB1 = quad_perm(1,0,3,2) = lane^1; 0x4E = quad_perm(2,3,0,1)
// = lane^2; 0x128 = row_ror:8 = lane^8 within 16-lane row; 0x124/0x12C =
// row_ror:4 / row_ror:12 (together + select = lane^4 exchange).
template<int CTRL>
__device__ __forceinline__ float dpp_add(float keep, float send) {
    const int r = __builtin_amdgcn_update_dpp(0, __float_as_int(send),
                                              CTRL, 0xF, 0xF, true);
    return keep + __int_as_float(r);
}
template<int CTRL>
__device__ __forceinline__ float dpp_mov(float send) {
    const int r = __builtin_amdgcn_update_dpp(0, __float_as_int(send),
                                              CTRL, 0xF, 0xF, true);
    return __int_as_float(r);
}

// Pin a scalar into a register (loads can't sink past the volatile asm).
#define PIN(x) asm volatile("" : "+v"(x))
#define PIN4(v4) PIN(v4.x); PIN(v4.y); PIN(v4.z); PIN(v4.w)

// LDS-visibility-only barrier: does NOT drain vmcnt (output stores stay in
// flight; they need no ordering with the barrier).
#define STEP_BARRIER() do {                                   \
    asm volatile("s_waitcnt lgkmcnt(0)" ::: "memory");        \
    __builtin_amdgcn_s_barrier();                             \
    asm volatile("" ::: "memory");                            \
} while (0)

// ---------------------------------------------------------------------------
// Kernel 1: precompute type-dependent tables into d_ws (f32).
//   tabH[ty][r] = sum_k embed_W[ty][k]*W_ih[r][k] + b_ih[r] + b_hh[r]
//   tabD[ty][r] = sum_k embed_W[ty][k]*dec_W[r][k] + dec_b[r]
// ---------------------------------------------------------------------------
__global__ __launch_bounds__(128) void precompute_tables(
    const float* __restrict__ embed_W, const float* __restrict__ W_ih,
    const float* __restrict__ b_ih,    const float* __restrict__ b_hh,
    const float* __restrict__ dec_W,   const float* __restrict__ dec_b,
    float* __restrict__ tabH, float* __restrict__ tabD)
{
    __shared__ float x[KD];
    const int ty = blockIdx.x;   // 0..64 (row 64 = padding, embed row is zero)
    const int r  = threadIdx.x;  // 0..127
    if (r < KD) x[r] = embed_W[ty * KD + r];
    __syncthreads();
    float ah = 0.f, ad = 0.f;
#pragma unroll
    for (int k = 0; k < KD; ++k) {
        const float xv = x[k];
        ah += xv * W_ih[r * KD + k];
        ad += xv * dec_W[r * (KD + HD) + k];
    }
    tabH[ty * HD + r] = ah + b_ih[r] + b_hh[r];
    tabD[ty * HD + r] = ad + dec_b[r];
}

// ---------------------------------------------------------------------------
// Kernel 2: persistent per-batch-element recurrence. One WG per batch elem,
// 512 threads = 8 waves. Lane bits (lane = tid&63):
//   b0,b1: row-low bits AND chunk bits 0,1 (value-halving butterfly)
//   b2: type (0=hidden/W_hh, 1=decay/dec_W)
//   b3: chunk bit 2 / duplicate tag
//   bits4-5 + wave: row quad G = wave*4 + ((lane>>4)&3)
// chunk = b0|b1<<1|b3<<2 (8 chunks x 16 h-cols); row = 4G + 2*b0 + b1.
// Dot engine: f32 weights (4 rows x 16 cols = 64 regs, pinned) x f32 h chunk
// (4 broadcast ds_read_b128) with NATIVE v_fma_f32 — the f16 fdot2 path of
// rounds 7-8 scalarized (no v_dot2_f32_f16 on gfx950) to ~5-6 insts/dot2,
// tripling the VALU instruction count.
// Reduction all-DPP: xor1/xor2 value-halving, xor8 plain add. Type exchange
// lane^4 via row_ror:4/12 + select. Each lane does EXACTLY ONE output task:
// (b2,b3)=(0,0) store hidden, (0,1) store hidden_ti, (1,0) store decay,
// (1,1) LDS-write h_new.
// h double-buffered in LDS f32; ONE lgkm-only barrier per step; 2x unrolled.
// ---------------------------------------------------------------------------
__global__ __launch_bounds__(512, 2) void hawkes_rnn(
    const float* __restrict__ dt_g,  const float* __restrict__ h0,
    const float* __restrict__ W_hh,  const float* __restrict__ dec_W,
    const int*   __restrict__ seq_types,
    const float* __restrict__ tabH,  const float* __restrict__ tabD,
    float* __restrict__ out)
{
    __shared__ float dts[SEQ];                        // 8,192 B
    __shared__ int   tys[SEQ + 2];                    // 8,200 B
    __shared__ __align__(16) float hs[2][HD];         // 1,024 B

    const int b    = blockIdx.x;
    const int tid  = threadIdx.x;
    const int lane = tid & 63;
    const int b0 = lane & 1, b1 = (lane >> 1) & 1;
    const int b2 = (lane >> 2) & 1, b3 = (lane >> 3) & 1;
    const int G    = (tid >> 6) * 4 + ((lane >> 4) & 3);  // row quad 0..31
    const int row  = 4 * G + 2 * b0 + b1;
    const int chunk = b0 | (b1 << 1) | (b3 << 2);         // h-col block /16
    const bool cls3 = (b2 & b3);                          // LDS-writer lane

    // Stage dt / seq_types columns for this batch element.
    for (int t = tid; t < SEQ; t += 512) {
        dts[t] = dt_g[(size_t)t * BAT + b];
        tys[t] = seq_types[(size_t)t * BAT + b];
    }
    if (tid < 2) tys[SEQ + tid] = 0;          // prefetch-pad
    if (tid < HD) hs[0][tid] = h0[b * HD + tid];

    // Load this lane's weight block (4 rows x 16 cols, f32) into NAMED
    // registers and pin them (stay resident; unified VGPR/AGPR file sources
    // either class directly for v_fma_f32).
    const size_t rstr = b2 ? (size_t)(KD + HD) : (size_t)HD;
    const float* wb = (b2 ? (dec_W + KD) : W_hh) + (size_t)(4 * G) * rstr
                      + chunk * 16;
    float4 w0_0 = *reinterpret_cast<const float4*>(wb + 0 * rstr + 0);
    float4 w0_1 = *reinterpret_cast<const float4*>(wb + 0 * rstr + 4);
    float4 w0_2 = *reinterpret_cast<const float4*>(wb + 0 * rstr + 8);
    float4 w0_3 = *reinterpret_cast<const float4*>(wb + 0 * rstr + 12);
    float4 w1_0 = *reinterpret_cast<const float4*>(wb + 1 * rstr + 0);
    float4 w1_1 = *reinterpret_cast<const float4*>(wb + 1 * rstr + 4);
    float4 w1_2 = *reinterpret_cast<const float4*>(wb + 1 * rstr + 8);
    float4 w1_3 = *reinterpret_cast<const float4*>(wb + 1 * rstr + 12);
    float4 w2_0 = *reinterpret_cast<const float4*>(wb + 2 * rstr + 0);
    float4 w2_1 = *reinterpret_cast<const float4*>(wb + 2 * rstr + 4);
    float4 w2_2 = *reinterpret_cast<const float4*>(wb + 2 * rstr + 8);
    float4 w2_3 = *reinterpret_cast<const float4*>(wb + 2 * rstr + 12);
    float4 w3_0 = *reinterpret_cast<const float4*>(wb + 3 * rstr + 0);
    float4 w3_1 = *reinterpret_cast<const float4*>(wb + 3 * rstr + 4);
    float4 w3_2 = *reinterpret_cast<const float4*>(wb + 3 * rstr + 8);
    float4 w3_3 = *reinterpret_cast<const float4*>(wb + 3 * rstr + 12);
    PIN4(w0_0); PIN4(w0_1); PIN4(w0_2); PIN4(w0_3);
    PIN4(w1_0); PIN4(w1_1); PIN4(w1_2); PIN4(w1_3);
    PIN4(w2_0); PIN4(w2_1); PIN4(w2_2); PIN4(w2_3);
    PIN4(w3_0); PIN4(w3_1); PIN4(w3_2); PIN4(w3_3);

    const float* tabp = (b2 ? tabD : tabH) + row;

    // Per-lane 32-bit element offset for the single global store this lane
    // owns (advanced by BAT*HD per step). Class 3 never stores.
    unsigned off = (unsigned)(b2 ? (b3 ? 0u : (unsigned)SEQ * BAT * HD)
                                 : (b3 ? 2u * SEQ * BAT * HD : 0u))
                   + (unsigned)(b * HD + row);

    __syncthreads();   // staging (dt/ty/h0) visible

    // Table prefetch pipeline (2 steps ahead; tables are L2-resident).
    float tab_cur = tabp[tys[0] * HD];
    float tab_nxt = tabp[tys[1] * HD];

#define ROWDOT(A, W0, W1, W2, W3) \
    A = fmaf(W0.x, hv0.x, A); A = fmaf(W0.y, hv0.y, A); \
    A = fmaf(W0.z, hv0.z, A); A = fmaf(W0.w, hv0.w, A); \
    A = fmaf(W1.x, hv1.x, A); A = fmaf(W1.y, hv1.y, A); \
    A = fmaf(W1.z, hv1.z, A); A = fmaf(W1.w, hv1.w, A); \
    A = fmaf(W2.x, hv2.x, A); A = fmaf(W2.y, hv2.y, A); \
    A = fmaf(W2.z, hv2.z, A); A = fmaf(W2.w, hv2.w, A); \
    A = fmaf(W3.x, hv3.x, A); A = fmaf(W3.y, hv3.y, A); \
    A = fmaf(W3.z, hv3.z, A); A = fmaf(W3.w, hv3.w, A);

#define STEP(P, TT) { \
    const float tab_pf = tabp[tys[(TT) + 2] * HD];   /* use at TT+2 */ \
    const float dtv    = dts[TT]; \
    /* h chunk: 4 broadcast ds_read_b128 (16 f32) */ \
    const float4 hv0 = *reinterpret_cast<const float4*>(&hs[P][chunk * 16]); \
    const float4 hv1 = *reinterpret_cast<const float4*>(&hs[P][chunk * 16 + 4]); \
    const float4 hv2 = *reinterpret_cast<const float4*>(&hs[P][chunk * 16 + 8]); \
    const float4 hv3 = *reinterpret_cast<const float4*>(&hs[P][chunk * 16 + 12]); \
    float a0 = 0.f, a1 = 0.f, a2 = 0.f, a3 = 0.f; \
    ROWDOT(a0, w0_0, w0_1, w0_2, w0_3) \
    ROWDOT(a1, w1_0, w1_1, w1_2, w1_3) \
    ROWDOT(a2, w2_0, w2_1, w2_2, w2_3) \
    ROWDOT(a3, w3_0, w3_1, w3_2, w3_3) \
    /* value-halving: xor1 resolves row-bit1, xor2 resolves row-bit0 */ \
    const float t0 = dpp_add<0xB1>(b0 ? a2 : a0, b0 ? a0 : a2); \
    const float t1 = dpp_add<0xB1>(b0 ? a3 : a1, b0 ? a1 : a3); \
    const float u  = dpp_add<0x4E>(b1 ? t1 : t0, b1 ? t0 : t1); \
    /* xor8 plain add completes the 8-chunk sum */ \
    const float sv = dpp_add<0x128>(u, u) + tab_cur; \
    /* activations (branchless; all lanes both paths) */ \
    const float e2 = __expf(2.f * sv); \
    const float vh = 1.f - __fdividef(2.f, e2 + 1.f);            /* tanh */ \
    const float z  = 10.f * sv; \
    const float em = __expf(-fabsf(z)); \
    const float sp = 0.1f * (fmaxf(z, 0.f) + __logf(1.f + em));  /* softplus10 */ \
    const float vd = __expf(-sp * dtv); \
    const float v  = b2 ? vd : vh; \
    /* type exchange lane^4: row_ror:4 / row_ror:12 + select */ \
    const float x4  = dpp_mov<0x124>(v); \
    const float x12 = dpp_mov<0x12C>(v); \
    const float cross = b2 ? x12 : x4; \
    const float hnew  = v * cross; \
    if (cls3) { \
        hs[(P) ^ 1][row] = hnew; \
    } else { \
        const float stv = b2 ? sp : (b3 ? hnew : v); \
        out[off] = stv; \
    } \
    off += BAT * HD; \
    tab_cur = tab_nxt; \
    tab_nxt = tab_pf; \
    STEP_BARRIER(); \
}

    for (int t = 0; t < SEQ; t += 2) {
        STEP(0, t)
        STEP(1, t + 1)
    }
#undef STEP
#undef ROWDOT
}

extern "C" void kernel_launch(void* const* d_in, const int* in_sizes, int n_in,
                              void* d_out, int out_size, void* d_ws, size_t ws_size,
                              hipStream_t stream) {
    const float* dt        = (const float*)d_in[0];
    const float* h0        = (const float*)d_in[1];
    const float* embed_W   = (const float*)d_in[2];
    const float* W_ih      = (const float*)d_in[3];
    const float* b_ih      = (const float*)d_in[4];
    const float* W_hh      = (const float*)d_in[5];
    const float* b_hh      = (const float*)d_in[6];
    const float* dec_W     = (const float*)d_in[7];
    const float* dec_b     = (const float*)d_in[8];
    const int*   seq_types = (const int*)  d_in[9];
    float* out  = (float*)d_out;

    float* tabHw = (float*)d_ws;                 // [65][128]
    float* tabDw = tabHw + (KD + 1) * HD;        // [65][128]

    precompute_tables<<<KD + 1, 128, 0, stream>>>(embed_W, W_ih, b_ih, b_hh,
                                                  dec_W, dec_b, tabHw, tabDw);
    hawkes_rnn<<<BAT, 512, 0, stream>>>(dt, h0, W_hh, dec_W, seq_types,
                                        tabHw, tabDw, out);
}